// Round 13
// baseline (161.766 us; speedup 1.0000x reference)
//
#include <hip/hip_runtime.h>
#include <hip/hip_cooperative_groups.h>
namespace cg = cooperative_groups;

#define Bn   4
#define Nn   1024
#define Mn   100
#define NB   25
#define FEAT 50
#define PIc  3.1415926f
#define RSTEP (5.5f / 24.0f)

#define ATB  16
#define NATOMS (Bn * Nn)
#define ORDER_LEN (NATOMS + ATB)        // 4112
#define NGRP (ORDER_LEN / ATB)          // 257
#define TYW  122880
#define GRID 256
#define THR  512
#define GPB  64
#define CPG  16

typedef __attribute__((ext_vector_type(8))) short bf16x8;
typedef __attribute__((ext_vector_type(4))) float f32x4;

union U16x8 { unsigned short u[8]; bf16x8 v; uint4 q; };

__device__ __forceinline__ unsigned short f2bh(float x) {
    union { float f; unsigned u; } v; v.f = x;
    unsigned r = v.u + 0x7fffu + ((v.u >> 16) & 1u);
    return (unsigned short)(r >> 16);
}
__device__ __forceinline__ float bh2f(unsigned short h) {
    union { unsigned u; float f; } v; v.u = ((unsigned)h) << 16; return v.f;
}
__device__ __forceinline__ float fast_tanh(float x) {
    float ax = fabsf(x);
    float t  = __expf(-2.0f * ax);
    float r  = (1.0f - t) * __builtin_amdgcn_rcpf(1.0f + t);
    return copysignf(r, x);
}

#define ISSUE(RH, RL, OFFU, OFFL, RW, NKT, HASLO, COND)                       \
    if (COND) {                                                               \
        int jj_ = c + 16 * w;                                                 \
        _Pragma("unroll")                                                     \
        for (int kt = 0; kt < (NKT); ++kt) {                                  \
            int boff_ = jj_ * (RW) + kt * 32 + q * 8;                         \
            RH[kt] = *(const bf16x8*)(wb + (OFFU) + boff_);                   \
            if (HASLO) RL[kt] = *(const bf16x8*)(wb + (OFFL) + boff_);        \
        }                                                                     \
    }

#define GEMM_R(ABUF, RH, RL, NKT, HASLO)                                      \
    {                                                                         \
        acc = (f32x4){0,0,0,0}; accl = (f32x4){0,0,0,0};                      \
        _Pragma("unroll")                                                     \
        for (int kt = 0; kt < (NKT); ++kt) {                                  \
            int gk = kt * 4 + q;                                              \
            bf16x8 af = *(const bf16x8*)&aA[ABUF][(c << 7) | ((gk ^ (c & 7)) << 3)]; \
            acc = __builtin_amdgcn_mfma_f32_16x16x32_bf16(af, RH[kt], acc, 0, 0, 0); \
            if (HASLO) accl = __builtin_amdgcn_mfma_f32_16x16x32_bf16(af, RL[kt], accl, 0, 0, 0); \
        }                                                                     \
    }

#define WRACT(BUF, J, A, X)                                                   \
    aA[BUF][((A) << 7) | ((((J) >> 3) ^ ((A) & 7)) << 3) | ((J) & 7)] = f2bh(X)

__global__ __launch_bounds__(THR, 2) void fused_kernel(
    const int* __restrict__ itype, const int* __restrict__ nlist,
    const float* __restrict__ dR,
    const float* __restrict__ W0, const float* __restrict__ B0,
    const float* __restrict__ W1, const float* __restrict__ B1,
    const float* __restrict__ W2, const float* __restrict__ B2,
    const float* __restrict__ W3, const float* __restrict__ B3,
    float* __restrict__ Etot, float* __restrict__ Ei, float* __restrict__ Force,
    float* __restrict__ dEp, int* __restrict__ order,
    unsigned short* __restrict__ wsu, float* __restrict__ partial)
{
    cg::grid_group grid = cg::this_grid();
    const int blk = blockIdx.x;
    const int t = threadIdx.x;

    __shared__ float tile[64][65];
    __shared__ int scan[THR];
    __shared__ float2 pairsh[ATB * Mn];
    __shared__ unsigned short aA[2][2048];
    __shared__ float fshf[16][52];
    __shared__ float dx1s[16][112];
    __shared__ float biasS[4][128];
    __shared__ float eip[8][16];
    __shared__ int aid[16];
    __shared__ float facc[(Nn + 1) * 3];
    __shared__ float desh[CPG][FEAT];

    // ================= Phase A: weight repack + sort =================
    if (blk < 20) {
        int ty = blk / 10, m = blk - ty * 10;
        int mat, jt, kt;
        if (m < 2)      { mat = 0; jt = m;            kt = 0; }
        else if (m < 6) { mat = 1; jt = (m - 2) >> 1; kt = (m - 2) & 1; }
        else            { mat = 2; jt = (m - 6) >> 1; kt = (m - 6) & 1; }
        const float* src = (mat == 0) ? W0 + ty * 5000
                          : (mat == 1) ? W1 + ty * 10000 : W2 + ty * 10000;
        const int Krows = (mat == 0) ? 50 : 100;
        const int Ck    = (mat == 0) ? 64 : 128;
        const int dH = ty * TYW + ((mat == 0) ? 0 : (mat == 1) ? 16384 : 49152);
        const int dL = dH + ((mat == 0) ? 8192 : 16384);
        const int j0 = jt * 64, k0 = kt * 64;
        const int rr0 = t >> 6, l = t & 63;
        #pragma unroll
        for (int i = 0; i < 8; ++i) {
            int rr = rr0 + 8 * i;
            int k = k0 + rr, j = j0 + l;
            tile[rr][l] = (k < Krows && j < 100) ? src[k * 100 + j] : 0.0f;
        }
        __syncthreads();
        #pragma unroll
        for (int i = 0; i < 8; ++i) {
            int jj = rr0 + 8 * i;
            float v = tile[l][jj];
            unsigned short h = f2bh(v);
            wsu[dH + (j0 + jj) * Ck + k0 + l] = h;
            wsu[dL + (j0 + jj) * Ck + k0 + l] = f2bh(v - bh2f(h));
        }
    } else if (blk < 180) {
        int e = (blk - 20) * THR + t;          // < 81920
        int ty = e / 40960;
        int r  = e - ty * 40960;
        float v = 0.0f; int dst;
        if (r < 16384) {
            int i = r >> 7, j = r & 127;
            if (i < 100 && j < 100) v = W2[ty * 10000 + i * 100 + j];
            dst = ty * TYW + 81920 + r;
        } else if (r < 32768) {
            int r2 = r - 16384; int i = r2 >> 7, j = r2 & 127;
            if (i < 100 && j < 100) v = W1[ty * 10000 + i * 100 + j];
            dst = ty * TYW + 98304 + r2;
        } else {
            int r2 = r - 32768; int f = r2 >> 7, j = r2 & 127;
            if (f < 50 && j < 100) v = W0[ty * 5000 + f * 100 + j];
            dst = ty * TYW + 114688 + r2;
        }
        wsu[dst] = f2bh(v);
    } else if (blk == 180) {
        for (int i = t; i < ORDER_LEN; i += THR) order[i] = -1;
        int tyv[8]; int c0 = 0;
        #pragma unroll
        for (int k = 0; k < 8; ++k) {
            int tt = (itype[t * 8 + k] == 8) ? 1 : 0;
            tyv[k] = tt; c0 += 1 - tt;
        }
        scan[t] = c0;
        __syncthreads();
        for (int off = 1; off < THR; off <<= 1) {
            int v = scan[t];
            int add = (t >= off) ? scan[t - off] : 0;
            __syncthreads();
            scan[t] = v + add;
            __syncthreads();
        }
        int total0 = scan[THR - 1];
        int ex0 = scan[t] - c0;
        int ex1 = 8 * t - ex0;
        int pad0 = (total0 + (ATB - 1)) & ~(ATB - 1);
        int p0 = ex0, p1 = pad0 + ex1;
        #pragma unroll
        for (int k = 0; k < 8; ++k) {
            int idx = t * 8 + k;
            if (tyv[k] == 0) order[p0++] = idx; else order[p1++] = idx;
        }
    }
    grid.sync();

    // ================= Phase B: mlp (inline feat), grid-strided =========
    {
        const int w = t >> 6;
        const int lane = t & 63;
        const int c = lane & 15, q = lane >> 4;

        for (int grp = blk; grp < NGRP; grp += GRID) {
            __syncthreads();
            if (t < 16) aid[t] = order[grp * ATB + t];
            __syncthreads();
            int first = -1;
            #pragma unroll
            for (int a = 0; a < ATB; ++a) { int v = aid[a]; if (first < 0 && v >= 0) first = v; }
            if (first < 0) continue;
            const int ty = (itype[first] == 8) ? 1 : 0;
            const unsigned short* wb = wsu + (size_t)ty * TYW;

            bf16x8 bh0[4], bl0[4], bh1[4], bl1[4];
            f32x4 acc, accl;
            float xr[4], h0r[4], h1r[4], h2r[4], dxr[4];

            ISSUE(bh0, bl0, 0, 8192, 64, 2, 1, true);

            for (int p = t; p < ATB * Mn; p += THR) {
                int a = p / Mn, m = p - a * Mn;
                int v = aid[a];
                float2 pr = make_float2(0.0f, 0.0f);
                if (v >= 0) {
                    float4 qv = ((const float4*)dR)[(size_t)v * Mn + m];
                    int nb = nlist[(size_t)v * Mn + m];
                    float r = qv.x;
                    if (nb > 0 && r > 0.0f && r < 6.0f) {
                        float cw = 0.5f * __cosf(PIc * r) + 0.5f;
                        pr = make_float2(r, (itype[(v >> 10) * Nn + nb - 1] == 8) ? -cw : cw);
                    } else pr.x = r;
                }
                pairsh[p] = pr;
            }
            {
                int row = t >> 7, col = t & 127;
                const float* s = (row == 0) ? B0 : (row == 1) ? B1 : (row == 2) ? B2 : W3;
                biasS[row][col] = (col < 100) ? s[ty * 100 + col] : 0.0f;
            }
            __syncthreads();

            for (int u = t; u < ATB * FEAT; u += THR) {
                int a = u / FEAT, l = u - a * FEAT;
                int tt = l / NB;
                float rk = 0.5f + (l - tt * NB) * RSTEP;
                float s = 0.0f;
                const float2* pp = &pairsh[a * Mn];
                #pragma unroll 4
                for (int m = 0; m < Mn; ++m) {
                    float2 pr = pp[m];
                    float cc2 = tt ? fmaxf(-pr.y, 0.0f) : fmaxf(pr.y, 0.0f);
                    float d = pr.x - rk;
                    s += __expf(-d * d) * cc2;
                }
                fshf[a][l] = s;
            }
            __syncthreads();

            if (t < 128) {
                const int srow = t >> 3, sg = t & 7;
                U16x8 pk;
                #pragma unroll
                for (int j7 = 0; j7 < 8; ++j7) {
                    int k = sg * 8 + j7;
                    pk.u[j7] = (k < FEAT) ? f2bh(fshf[srow][k]) : 0;
                }
                *(uint4*)&aA[0][(srow << 7) | ((sg ^ (srow & 7)) << 3)] = pk.q;
            }
            __syncthreads();

            // P0
            ISSUE(bh1, bl1, 16384, 32768, 128, 4, 1, true);
            GEMM_R(0, bh0, bl0, 2, 1);
            {
                int j = c + 16 * w;
                float bj = biasS[0][j];
                #pragma unroll
                for (int r = 0; r < 4; ++r) {
                    int a = q * 4 + r;
                    float z = acc[r] + accl[r] + bj;
                    float h = 0.f, x = 0.f;
                    if (j < 100) { h = fast_tanh(z); x = h + fshf[a][(j < 50) ? j : j - 50]; }
                    h0r[r] = h; xr[r] = x;
                    WRACT(1, j, a, x);
                }
            }
            __syncthreads();

            // P1
            ISSUE(bh0, bl0, 49152, 65536, 128, 4, 1, true);
            GEMM_R(1, bh1, bl1, 4, 1);
            {
                int j = c + 16 * w;
                float bj = biasS[1][j];
                #pragma unroll
                for (int r = 0; r < 4; ++r) {
                    int a = q * 4 + r;
                    float z = acc[r] + accl[r] + bj;
                    float h = (j < 100) ? fast_tanh(z) : 0.f;
                    float x = (j < 100) ? (h + xr[r]) : 0.f;
                    h1r[r] = h; xr[r] = x;
                    WRACT(0, j, a, x);
                }
            }
            __syncthreads();

            // P2
            ISSUE(bh1, bl1, 81920, 0, 128, 4, 0, true);
            GEMM_R(0, bh0, bl0, 4, 1);
            {
                int j = c + 16 * w;
                float bj = biasS[2][j];
                float wv = biasS[3][j];
                float p4v[4];
                #pragma unroll
                for (int r = 0; r < 4; ++r) {
                    float z = acc[r] + accl[r] + bj;
                    float h = (j < 100) ? fast_tanh(z) : 0.f;
                    h2r[r] = h;
                    xr[r] = (j < 100) ? (h + xr[r]) : 0.f;
                    p4v[r] = xr[r] * wv;
                }
                #pragma unroll
                for (int off = 1; off < 16; off <<= 1) {
                    #pragma unroll
                    for (int r = 0; r < 4; ++r) p4v[r] += __shfl_xor(p4v[r], off);
                }
                if (c == 0) {
                    #pragma unroll
                    for (int r = 0; r < 4; ++r) eip[w][q * 4 + r] = p4v[r];
                }
                #pragma unroll
                for (int r = 0; r < 4; ++r) {
                    int a = q * 4 + r;
                    float d = wv * (1.0f - h2r[r] * h2r[r]);
                    WRACT(1, j, a, d);
                }
            }
            __syncthreads();
            if (t < 16) {
                int v = aid[t];
                if (v >= 0) {
                    float e = B3[ty];
                    #pragma unroll
                    for (int ww = 0; ww < 8; ++ww) e += eip[ww][t];
                    Ei[v] = e;
                }
            }

            // P3
            ISSUE(bh0, bl0, 98304, 0, 128, 4, 0, true);
            GEMM_R(1, bh1, bl1, 4, 0);
            {
                int i = c + 16 * w;
                float w3i = biasS[3][i];
                #pragma unroll
                for (int r = 0; r < 4; ++r) {
                    int a = q * 4 + r;
                    float dx2 = acc[r] + w3i;
                    dxr[r] = dx2;
                    float d = dx2 * (1.0f - h1r[r] * h1r[r]);
                    WRACT(0, i, a, d);
                }
            }
            __syncthreads();

            // P4
            ISSUE(bh1, bl1, 114688, 0, 128, 4, 0, (w < 4));
            GEMM_R(0, bh0, bl0, 4, 0);
            {
                int i = c + 16 * w;
                #pragma unroll
                for (int r = 0; r < 4; ++r) {
                    int a = q * 4 + r;
                    float dx1 = dxr[r] + acc[r];
                    if (i < 112) dx1s[a][i] = dx1;
                    float d = dx1 * (1.0f - h0r[r] * h0r[r]);
                    WRACT(1, i, a, d);
                }
            }
            __syncthreads();

            // P5
            if (w < 4) {
                GEMM_R(1, bh1, bl1, 4, 0);
                int f = c + 16 * w;
                if (f < 50) {
                    #pragma unroll
                    for (int r = 0; r < 4; ++r) {
                        int a = q * 4 + r;
                        int v = aid[a];
                        if (v >= 0) dEp[(size_t)v * FEAT + f] = acc[r] + dx1s[a][f] + dx1s[a][f + 50];
                    }
                }
            }
        }
    }
    grid.sync();

    // ================= Phase C: force partials =================
    {
        const int b = blk >> 6;          // / GPB
        const int g = blk & 63;
        for (int idx = t; idx < (Nn + 1) * 3; idx += THR) facc[idx] = 0.0f;
        for (int idx = t; idx < CPG * FEAT; idx += THR)
            ((float*)desh)[idx] = dEp[((size_t)(b * Nn) + g * CPG) * FEAT + idx];
        __syncthreads();

        for (int p = t; p < CPG * Mn; p += THR) {
            int cc = p / Mn, m = p - cc * Mn;
            int n = g * CPG + cc;
            size_t pair = (size_t)(b * Nn + n) * Mn + m;
            float4 qv = ((const float4*)dR)[pair];
            int v = nlist[pair];
            if (v > 0) {
                float r = qv.x;
                if (r > 0.0f && r < 6.0f) {
                    int tt = (itype[b * Nn + v - 1] == 8) ? 1 : 0;
                    float cw  = 0.5f * __cosf(PIc * r) + 0.5f;
                    float dcw = -0.5f * PIc * __sinf(PIc * r);
                    float s = 0.0f;
                    const float* de = &desh[cc][tt * NB];
                    #pragma unroll
                    for (int k = 0; k < NB; ++k) {
                        float d = r - (0.5f + k * RSTEP);
                        float e = __expf(-d * d);
                        s += de[k] * e * __builtin_fmaf(-2.0f * cw, d, dcw);
                    }
                    float inv = 1.0f / r;
                    float fx = s * qv.y * inv, fy = s * qv.z * inv, fz = s * qv.w * inv;
                    atomicAdd(&facc[v * 3 + 0], fx);
                    atomicAdd(&facc[v * 3 + 1], fy);
                    atomicAdd(&facc[v * 3 + 2], fz);
                    atomicAdd(&facc[(n + 1) * 3 + 0], -fx);
                    atomicAdd(&facc[(n + 1) * 3 + 1], -fy);
                    atomicAdd(&facc[(n + 1) * 3 + 2], -fz);
                }
            }
        }
        __syncthreads();

        float* pout = partial + (size_t)blk * ((Nn + 1) * 3);
        for (int idx = t; idx < (Nn + 1) * 3; idx += THR) pout[idx] = facc[idx];
    }
    grid.sync();

    // ================= Phase D: Force reduce + Etot =================
    {
        int gid = blk * THR + t;
        if (gid < Bn * Nn * 3) {
            int b = gid / (Nn * 3);
            int r = gid - b * (Nn * 3);
            float s = 0.0f;
            #pragma unroll 8
            for (int g = 0; g < GPB; ++g)
                s += partial[(size_t)(b * GPB + g) * ((Nn + 1) * 3) + 3 + r];
            Force[gid] = s;
        }
        if (blk < Bn) {
            float s = 0.0f;
            for (int i = t; i < Nn; i += THR) s += Ei[blk * Nn + i];
            scan[t] = __float_as_int(s);
            __syncthreads();
            for (int st = THR / 2; st > 0; st >>= 1) {
                if (t < st) scan[t] = __float_as_int(__int_as_float(scan[t]) + __int_as_float(scan[t + st]));
                __syncthreads();
            }
            if (t == 0) Etot[blk] = __int_as_float(scan[0]);
        }
    }
}

// -------------------------------------------------------------- launch ----
extern "C" void kernel_launch(void* const* d_in, const int* in_sizes, int n_in,
                              void* d_out, int out_size, void* d_ws, size_t ws_size,
                              hipStream_t stream)
{
    const int*   itype = (const int*)d_in[0];
    const int*   nlist = (const int*)d_in[1];
    const float* dR    = (const float*)d_in[2];
    const float* W0 = (const float*)d_in[3];  const float* B0 = (const float*)d_in[4];
    const float* W1 = (const float*)d_in[5];  const float* B1 = (const float*)d_in[6];
    const float* W2 = (const float*)d_in[7];  const float* B2 = (const float*)d_in[8];
    const float* W3 = (const float*)d_in[9];  const float* B3 = (const float*)d_in[10];

    float* out   = (float*)d_out;
    float* Etot  = out;                    // [B,1]
    float* Ei    = out + Bn;               // [B,N,1]
    float* Force = out + Bn + Bn * Nn;     // [B,N,3]

    float* dEp     = (float*)d_ws;                                  // NATOMS*50
    float* partial = dEp + (size_t)NATOMS * FEAT;                   // 256*3075
    int*   order   = (int*)(partial + (size_t)GRID * (Nn + 1) * 3); // ORDER_LEN
    unsigned short* wsu = (unsigned short*)(order + ORDER_LEN);     // 2*TYW

    void* args[] = { (void*)&itype, (void*)&nlist, (void*)&dR,
                     (void*)&W0, (void*)&B0, (void*)&W1, (void*)&B1,
                     (void*)&W2, (void*)&B2, (void*)&W3, (void*)&B3,
                     (void*)&Etot, (void*)&Ei, (void*)&Force,
                     (void*)&dEp, (void*)&order, (void*)&wsu, (void*)&partial };
    hipLaunchCooperativeKernel((void*)fused_kernel, dim3(GRID), dim3(THR),
                               args, 0, stream);
}

// Round 14
// 60.237 us; speedup vs baseline: 2.6855x; 2.6855x over previous
//
#include <hip/hip_runtime.h>

#define Bn   4
#define Nn   1024
#define Mn   100
#define NB   25
#define FEAT 50
#define PIc  3.1415926f
#define RSTEP (5.5f / 24.0f)

#define ATB  16                         // atoms per MLP block
#define NATOMS (Bn * Nn)
#define ORDER_LEN (NATOMS + ATB)        // 4112
#define MLP_BLOCKS (ORDER_LEN / ATB)    // 257
#define TYW  122880                     // ushorts per type in wsu

#define GPB  64                         // force groups per batch (256 blocks)
#define CPG  16
#define FTHREADS 512

typedef __attribute__((ext_vector_type(8))) short bf16x8;
typedef __attribute__((ext_vector_type(4))) float f32x4;

union U16x8 { unsigned short u[8]; bf16x8 v; uint4 q; };

__device__ __forceinline__ unsigned short f2bh(float x) {
    union { float f; unsigned u; } v; v.f = x;
    unsigned r = v.u + 0x7fffu + ((v.u >> 16) & 1u);
    return (unsigned short)(r >> 16);
}
__device__ __forceinline__ float bh2f(unsigned short h) {
    union { unsigned u; float f; } v; v.u = ((unsigned)h) << 16; return v.f;
}
__device__ __forceinline__ float fast_tanh(float x) {
    float ax = fabsf(x);
    float t  = __expf(-2.0f * ax);
    float r  = (1.0f - t) * __builtin_amdgcn_rcpf(1.0f + t);
    return copysignf(r, x);
}

// wsu layout per type (ushort offsets):
// 0      WT0h [128j][64k]   8192   (fwd L0 hi)     8192 WT0l
// 16384  WT1h [128j][128k] 16384   32768 WT1l
// 49152  WT2h             16384    65536 WT2l
// 81920  WRM2 [128i][128j] 16384   (bwd hi only)
// 98304  WRM1             16384
// 114688 WRM0 [64f][128j]  8192

// ------------------------------------------------ prep: repack + sort -----
__global__ __launch_bounds__(256) void prep_kernel(
    const int* __restrict__ itype,
    const float* __restrict__ W0, const float* __restrict__ W1,
    const float* __restrict__ W2,
    int* __restrict__ order, unsigned short* __restrict__ wsu)
{
    const int blk = blockIdx.x;
    const int t = threadIdx.x;

    if (blk < 20) {
        __shared__ float tile[64][65];
        int ty = blk / 10, m = blk - ty * 10;
        int mat, jt, kt;
        if (m < 2)      { mat = 0; jt = m;            kt = 0; }
        else if (m < 6) { mat = 1; jt = (m - 2) >> 1; kt = (m - 2) & 1; }
        else            { mat = 2; jt = (m - 6) >> 1; kt = (m - 6) & 1; }
        const float* src = (mat == 0) ? W0 + ty * 5000
                          : (mat == 1) ? W1 + ty * 10000 : W2 + ty * 10000;
        const int Krows = (mat == 0) ? 50 : 100;
        const int Ck    = (mat == 0) ? 64 : 128;
        const int dH = ty * TYW + ((mat == 0) ? 0 : (mat == 1) ? 16384 : 49152);
        const int dL = dH + ((mat == 0) ? 8192 : 16384);
        const int j0 = jt * 64, k0 = kt * 64;
        const int rr0 = t >> 6, l = t & 63;
        #pragma unroll
        for (int i = 0; i < 16; ++i) {
            int rr = rr0 + 4 * i;
            int k = k0 + rr, j = j0 + l;
            tile[rr][l] = (k < Krows && j < 100) ? src[k * 100 + j] : 0.0f;
        }
        __syncthreads();
        #pragma unroll
        for (int i = 0; i < 16; ++i) {
            int jj = rr0 + 4 * i;
            float v = tile[l][jj];
            unsigned short h = f2bh(v);
            wsu[dH + (j0 + jj) * Ck + k0 + l] = h;
            wsu[dL + (j0 + jj) * Ck + k0 + l] = f2bh(v - bh2f(h));
        }
        return;
    }
    if (blk < 340) {
        int e = (blk - 20) * 256 + t;          // < 81920
        int ty = e / 40960;
        int r  = e - ty * 40960;
        float v = 0.0f; int dst;
        if (r < 16384) {            // WRM2
            int i = r >> 7, j = r & 127;
            if (i < 100 && j < 100) v = W2[ty * 10000 + i * 100 + j];
            dst = ty * TYW + 81920 + r;
        } else if (r < 32768) {     // WRM1
            int r2 = r - 16384; int i = r2 >> 7, j = r2 & 127;
            if (i < 100 && j < 100) v = W1[ty * 10000 + i * 100 + j];
            dst = ty * TYW + 98304 + r2;
        } else {                    // WRM0
            int r2 = r - 32768; int f = r2 >> 7, j = r2 & 127;
            if (f < 50 && j < 100) v = W0[ty * 5000 + f * 100 + j];
            dst = ty * TYW + 114688 + r2;
        }
        wsu[dst] = f2bh(v);
        return;
    }
    // sort block (blk == 340): type partition, pad each segment to ATB
    __shared__ int scan[256];
    for (int i = t; i < ORDER_LEN; i += 256) order[i] = -1;
    int tyv[16]; int c0 = 0;
    #pragma unroll
    for (int k = 0; k < 16; ++k) {
        int tt = (itype[t * 16 + k] == 8) ? 1 : 0;
        tyv[k] = tt; c0 += 1 - tt;
    }
    scan[t] = c0;
    __syncthreads();
    for (int off = 1; off < 256; off <<= 1) {
        int v = scan[t];
        int add = (t >= off) ? scan[t - off] : 0;
        __syncthreads();
        scan[t] = v + add;
        __syncthreads();
    }
    int total0 = scan[255];
    int ex0 = scan[t] - c0;
    int ex1 = 16 * t - ex0;
    int pad0 = (total0 + (ATB - 1)) & ~(ATB - 1);
    int p0 = ex0, p1 = pad0 + ex1;
    #pragma unroll
    for (int k = 0; k < 16; ++k) {
        int idx = t * 16 + k;
        if (tyv[k] == 0) order[p0++] = idx; else order[p1++] = idx;
    }
}

// ------------------------------------------------- mlp (with inline feat) --
// 512 thr = 8 waves, 16 type-pure atoms. Feat computed in-block (pair-stage
// to LDS, bell-parallel accumulate) while WT0 prefetch is in flight.
#define ISSUE(RH, RL, OFFU, OFFL, RW, NKT, HASLO, COND)                       \
    if (COND) {                                                               \
        int jj_ = c + 16 * w;                                                 \
        _Pragma("unroll")                                                     \
        for (int kt = 0; kt < (NKT); ++kt) {                                  \
            int boff_ = jj_ * (RW) + kt * 32 + q * 8;                         \
            RH[kt] = *(const bf16x8*)(wb + (OFFU) + boff_);                   \
            if (HASLO) RL[kt] = *(const bf16x8*)(wb + (OFFL) + boff_);        \
        }                                                                     \
    }

#define GEMM_R(ABUF, RH, RL, NKT, HASLO)                                      \
    {                                                                         \
        acc = (f32x4){0,0,0,0}; accl = (f32x4){0,0,0,0};                      \
        _Pragma("unroll")                                                     \
        for (int kt = 0; kt < (NKT); ++kt) {                                  \
            int gk = kt * 4 + q;                                              \
            bf16x8 af = *(const bf16x8*)&aA[ABUF][(c << 7) | ((gk ^ (c & 7)) << 3)]; \
            acc = __builtin_amdgcn_mfma_f32_16x16x32_bf16(af, RH[kt], acc, 0, 0, 0); \
            if (HASLO) accl = __builtin_amdgcn_mfma_f32_16x16x32_bf16(af, RL[kt], accl, 0, 0, 0); \
        }                                                                     \
    }

#define WRACT(BUF, J, A, X)                                                   \
    aA[BUF][((A) << 7) | ((((J) >> 3) ^ ((A) & 7)) << 3) | ((J) & 7)] = f2bh(X)

__global__ __launch_bounds__(512) void mlp_kernel(
    const float* __restrict__ dR, const int* __restrict__ nlist,
    const int* __restrict__ itype,
    const int* __restrict__ order, const unsigned short* __restrict__ wsu,
    const float* __restrict__ B0, const float* __restrict__ B1,
    const float* __restrict__ B2, const float* __restrict__ W3,
    const float* __restrict__ B3,
    float* __restrict__ Ei, float* __restrict__ dE)
{
    const int t = threadIdx.x;
    const int w = t >> 6;               // 0..7 : n-tile owner
    const int lane = t & 63;
    const int c = lane & 15, q = lane >> 4;

    __shared__ float2 pairsh[ATB * Mn];         // 12.8KB (r, +/-cw)
    __shared__ unsigned short aA[2][2048];      // 8KB pingpong
    __shared__ float fshf[16][52];
    __shared__ float dx1s[16][112];
    __shared__ float biasS[4][128];
    __shared__ float eip[8][16];
    __shared__ int aid[16];

    if (t < 16) aid[t] = order[blockIdx.x * ATB + t];
    __syncthreads();
    int first = -1;
    #pragma unroll
    for (int a = 0; a < ATB; ++a) { int v = aid[a]; if (first < 0 && v >= 0) first = v; }
    if (first < 0) return;
    const int ty = (itype[first] == 8) ? 1 : 0;
    const unsigned short* wb = wsu + (size_t)ty * TYW;

    bf16x8 bh0[4], bl0[4], bh1[4], bl1[4];
    f32x4 acc, accl;
    float xr[4], h0r[4], h1r[4], h2r[4], dxr[4];

    // ---- issue WT0 weight loads immediately (hide under feat compute) ----
    ISSUE(bh0, bl0, 0, 8192, 64, 2, 1, true);

    // ---- inline feat: stage pairs ----
    for (int p = t; p < ATB * Mn; p += 512) {
        int a = p / Mn, m = p - a * Mn;
        int v = aid[a];
        float2 pr = make_float2(0.0f, 0.0f);
        if (v >= 0) {
            float4 qv = ((const float4*)dR)[(size_t)v * Mn + m];
            int nb = nlist[(size_t)v * Mn + m];
            float r = qv.x;
            if (nb > 0 && r > 0.0f && r < 6.0f) {
                float cw = 0.5f * __cosf(PIc * r) + 0.5f;
                pr = make_float2(r, (itype[(v >> 10) * Nn + nb - 1] == 8) ? -cw : cw);
            } else pr.x = r;
        }
        pairsh[p] = pr;
    }
    // biases
    {
        int row = t >> 7, col = t & 127;
        const float* s = (row == 0) ? B0 : (row == 1) ? B1 : (row == 2) ? B2 : W3;
        biasS[row][col] = (col < 100) ? s[ty * 100 + col] : 0.0f;
    }
    __syncthreads();

    // ---- bells: 800 (atom,bell) units over 512 threads ----
    for (int u = t; u < ATB * FEAT; u += 512) {
        int a = u / FEAT, l = u - a * FEAT;
        int tt = l / NB;
        float rk = 0.5f + (l - tt * NB) * RSTEP;
        float s = 0.0f;
        const float2* pp = &pairsh[a * Mn];
        #pragma unroll 4
        for (int m = 0; m < Mn; ++m) {
            float2 pr = pp[m];
            float cc = tt ? fmaxf(-pr.y, 0.0f) : fmaxf(pr.y, 0.0f);
            float d = pr.x - rk;
            s += __expf(-d * d) * cc;
        }
        fshf[a][l] = s;
    }
    __syncthreads();

    // ---- pack feats to bf16 A-tile ----
    if (t < 128) {
        const int srow = t >> 3, sg = t & 7;
        U16x8 pk;
        #pragma unroll
        for (int j7 = 0; j7 < 8; ++j7) {
            int k = sg * 8 + j7;
            pk.u[j7] = (k < FEAT) ? f2bh(fshf[srow][k]) : 0;
        }
        *(uint4*)&aA[0][(srow << 7) | ((sg ^ (srow & 7)) << 3)] = pk.q;
    }
    __syncthreads();

    // ---- P0: L0 fwd (WT0 h+l, A=aA0 feat) -> x1 in aA1 ----
    ISSUE(bh1, bl1, 16384, 32768, 128, 4, 1, true);     // prefetch WT1
    GEMM_R(0, bh0, bl0, 2, 1);
    {
        int j = c + 16 * w;
        float bj = biasS[0][j];
        #pragma unroll
        for (int r = 0; r < 4; ++r) {
            int a = q * 4 + r;
            float z = acc[r] + accl[r] + bj;
            float h = 0.f, x = 0.f;
            if (j < 100) { h = fast_tanh(z); x = h + fshf[a][(j < 50) ? j : j - 50]; }
            h0r[r] = h; xr[r] = x;
            WRACT(1, j, a, x);
        }
    }
    __syncthreads();

    // ---- P1: L1 fwd -> x2 in aA0 ----
    ISSUE(bh0, bl0, 49152, 65536, 128, 4, 1, true);     // prefetch WT2
    GEMM_R(1, bh1, bl1, 4, 1);
    {
        int j = c + 16 * w;
        float bj = biasS[1][j];
        #pragma unroll
        for (int r = 0; r < 4; ++r) {
            int a = q * 4 + r;
            float z = acc[r] + accl[r] + bj;
            float h = (j < 100) ? fast_tanh(z) : 0.f;
            float x = (j < 100) ? (h + xr[r]) : 0.f;
            h1r[r] = h; xr[r] = x;
            WRACT(0, j, a, x);
        }
    }
    __syncthreads();

    // ---- P2: L2 fwd -> Ei partials, dz2 in aA1 ----
    ISSUE(bh1, bl1, 81920, 0, 128, 4, 0, true);         // prefetch WRM2
    GEMM_R(0, bh0, bl0, 4, 1);
    {
        int j = c + 16 * w;
        float bj = biasS[2][j];
        float wv = biasS[3][j];
        float p4v[4];
        #pragma unroll
        for (int r = 0; r < 4; ++r) {
            float z = acc[r] + accl[r] + bj;
            float h = (j < 100) ? fast_tanh(z) : 0.f;
            h2r[r] = h;
            xr[r] = (j < 100) ? (h + xr[r]) : 0.f;      // x3
            p4v[r] = xr[r] * wv;
        }
        #pragma unroll
        for (int off = 1; off < 16; off <<= 1) {
            #pragma unroll
            for (int r = 0; r < 4; ++r) p4v[r] += __shfl_xor(p4v[r], off);
        }
        if (c == 0) {
            #pragma unroll
            for (int r = 0; r < 4; ++r) eip[w][q * 4 + r] = p4v[r];
        }
        #pragma unroll
        for (int r = 0; r < 4; ++r) {
            int a = q * 4 + r;
            float d = wv * (1.0f - h2r[r] * h2r[r]);    // dz2
            WRACT(1, j, a, d);
        }
    }
    __syncthreads();
    if (t < 16) {
        int v = aid[t];
        if (v >= 0) {
            float e = B3[ty];
            #pragma unroll
            for (int ww = 0; ww < 8; ++ww) e += eip[ww][t];
            Ei[v] = e;
        }
    }

    // ---- P3: bwd2 -> dz1 in aA0 ----
    ISSUE(bh0, bl0, 98304, 0, 128, 4, 0, true);         // prefetch WRM1
    GEMM_R(1, bh1, bl1, 4, 0);
    {
        int i = c + 16 * w;
        float w3i = biasS[3][i];
        #pragma unroll
        for (int r = 0; r < 4; ++r) {
            int a = q * 4 + r;
            float dx2 = acc[r] + w3i;
            dxr[r] = dx2;
            float d = dx2 * (1.0f - h1r[r] * h1r[r]);   // dz1
            WRACT(0, i, a, d);
        }
    }
    __syncthreads();

    // ---- P4: bwd1 -> dz0 in aA1, dx1s ----
    ISSUE(bh1, bl1, 114688, 0, 128, 4, 0, (w < 4));     // prefetch WRM0
    GEMM_R(0, bh0, bl0, 4, 0);
    {
        int i = c + 16 * w;
        #pragma unroll
        for (int r = 0; r < 4; ++r) {
            int a = q * 4 + r;
            float dx1 = dxr[r] + acc[r];
            if (i < 112) dx1s[a][i] = dx1;
            float d = dx1 * (1.0f - h0r[r] * h0r[r]);   // dz0
            WRACT(1, i, a, d);
        }
    }
    __syncthreads();

    // ---- P5: bwd0 (N=64, waves 0-3) -> dE ----
    if (w < 4) {
        GEMM_R(1, bh1, bl1, 4, 0);
        int f = c + 16 * w;
        if (f < 50) {
            #pragma unroll
            for (int r = 0; r < 4; ++r) {
                int a = q * 4 + r;
                int v = aid[a];
                if (v >= 0) dE[(size_t)v * FEAT + f] = acc[r] + dx1s[a][f] + dx1s[a][f + 50];
            }
        }
    }
}

// --------------------------------------------------------------- force ----
__global__ __launch_bounds__(FTHREADS) void force_kernel(
    const int* __restrict__ itype, const int* __restrict__ nlist,
    const float* __restrict__ dR, const float* __restrict__ dE,
    float* __restrict__ partial)
{
    const int blk = blockIdx.x;
    const int b = blk / GPB;
    const int g = blk - b * GPB;
    const int t = threadIdx.x;

    __shared__ float acc[(Nn + 1) * 3];
    __shared__ float desh[CPG][FEAT];

    for (int idx = t; idx < (Nn + 1) * 3; idx += FTHREADS) acc[idx] = 0.0f;
    for (int idx = t; idx < CPG * FEAT; idx += FTHREADS)
        ((float*)desh)[idx] = dE[((size_t)(b * Nn) + g * CPG) * FEAT + idx];
    __syncthreads();

    for (int p = t; p < CPG * Mn; p += FTHREADS) {
        int cc = p / Mn, m = p - cc * Mn;
        int n = g * CPG + cc;
        size_t pair = (size_t)(b * Nn + n) * Mn + m;
        float4 qv = ((const float4*)dR)[pair];
        int v = nlist[pair];
        if (v > 0) {
            float r = qv.x;
            if (r > 0.0f && r < 6.0f) {
                int tt = (itype[b * Nn + v - 1] == 8) ? 1 : 0;
                float cw  = 0.5f * __cosf(PIc * r) + 0.5f;
                float dcw = -0.5f * PIc * __sinf(PIc * r);
                float s = 0.0f;
                const float* de = &desh[cc][tt * NB];
                #pragma unroll
                for (int k = 0; k < NB; ++k) {
                    float d = r - (0.5f + k * RSTEP);
                    float e = __expf(-d * d);
                    s += de[k] * e * __builtin_fmaf(-2.0f * cw, d, dcw);
                }
                float inv = 1.0f / r;
                float fx = s * qv.y * inv, fy = s * qv.z * inv, fz = s * qv.w * inv;
                atomicAdd(&acc[v * 3 + 0], fx);
                atomicAdd(&acc[v * 3 + 1], fy);
                atomicAdd(&acc[v * 3 + 2], fz);
                atomicAdd(&acc[(n + 1) * 3 + 0], -fx);
                atomicAdd(&acc[(n + 1) * 3 + 1], -fy);
                atomicAdd(&acc[(n + 1) * 3 + 2], -fz);
            }
        }
    }
    __syncthreads();

    float* pout = partial + (size_t)blk * ((Nn + 1) * 3);
    for (int idx = t; idx < (Nn + 1) * 3; idx += FTHREADS) pout[idx] = acc[idx];
}

// ----------------------------------------------------- freduce (+etot) ----
__global__ __launch_bounds__(256) void freduce_kernel(
    const float* __restrict__ partial, const float* __restrict__ Ei,
    float* __restrict__ Force, float* __restrict__ Etot)
{
    if (blockIdx.x == 48) {   // etot
        const int t = threadIdx.x;
        __shared__ float red[256];
        for (int b = 0; b < Bn; ++b) {
            float s = 0.0f;
            for (int i = t; i < Nn; i += 256) s += Ei[b * Nn + i];
            red[t] = s;
            __syncthreads();
            for (int st = 128; st > 0; st >>= 1) {
                if (t < st) red[t] += red[t + st];
                __syncthreads();
            }
            if (t == 0) Etot[b] = red[0];
            __syncthreads();
        }
        return;
    }
    int idx = blockIdx.x * 256 + threadIdx.x;
    if (idx >= Bn * Nn * 3) return;
    int b = idx / (Nn * 3);
    int r = idx - b * (Nn * 3);
    int i = r / 3, ch = r - i * 3;
    float s = 0.0f;
    for (int g = 0; g < GPB; ++g)
        s += partial[((size_t)(b * GPB + g)) * ((Nn + 1) * 3) + (size_t)(i + 1) * 3 + ch];
    Force[idx] = s;
}

// -------------------------------------------------------------- launch ----
extern "C" void kernel_launch(void* const* d_in, const int* in_sizes, int n_in,
                              void* d_out, int out_size, void* d_ws, size_t ws_size,
                              hipStream_t stream)
{
    const int*   itype = (const int*)d_in[0];
    const int*   nlist = (const int*)d_in[1];
    const float* dR    = (const float*)d_in[2];
    const float* W0 = (const float*)d_in[3];  const float* B0 = (const float*)d_in[4];
    const float* W1 = (const float*)d_in[5];  const float* B1 = (const float*)d_in[6];
    const float* W2 = (const float*)d_in[7];  const float* B2 = (const float*)d_in[8];
    const float* W3 = (const float*)d_in[9];  const float* B3 = (const float*)d_in[10];

    float* out   = (float*)d_out;
    float* Etot  = out;                    // [B,1]
    float* Ei    = out + Bn;               // [B,N,1]
    float* Force = out + Bn + Bn * Nn;     // [B,N,3]

    float* dEp     = (float*)d_ws;                              // NATOMS*50 f32
    float* partial = dEp + (size_t)NATOMS * FEAT;               // Bn*GPB*(Nn+1)*3
    int*   order   = (int*)(partial + (size_t)Bn * GPB * (Nn + 1) * 3);
    unsigned short* wsu = (unsigned short*)(order + ORDER_LEN); // 2*TYW ushorts

    prep_kernel   <<<341, 256, 0, stream>>>(itype, W0, W1, W2, order, wsu);
    mlp_kernel    <<<MLP_BLOCKS, 512, 0, stream>>>(dR, nlist, itype, order, wsu,
                                                   B0, B1, B2, W3, B3, Ei, dEp);
    force_kernel  <<<Bn * GPB, FTHREADS, 0, stream>>>(itype, nlist, dR, dEp, partial);
    freduce_kernel<<<49, 256, 0, stream>>>(partial, Ei, Force, Etot);
}

// Round 15
// 54.202 us; speedup vs baseline: 2.9845x; 1.1113x over previous
//
#include <hip/hip_runtime.h>

#define Bn   4
#define Nn   1024
#define Mn   100
#define NB   25
#define FEAT 50
#define PIc  3.1415926f
#define RSTEP (5.5f / 24.0f)

#define ATB  16                         // atoms per MLP block (all real)
#define NATOMS (Bn * Nn)
#define ORDER_LEN (NATOMS + ATB)        // 4112
#define MLP_BLOCKS (ORDER_LEN / ATB)    // 257
#define TYW  122880                     // ushorts per type in wsu

#define GPB  64
#define CPG  16
#define FTHREADS 512

typedef __attribute__((ext_vector_type(8))) short bf16x8;
typedef __attribute__((ext_vector_type(4))) float f32x4;

union U16x8 { unsigned short u[8]; bf16x8 v; uint4 q; };

__device__ __forceinline__ unsigned short f2bh(float x) {
    union { float f; unsigned u; } v; v.f = x;
    unsigned r = v.u + 0x7fffu + ((v.u >> 16) & 1u);
    return (unsigned short)(r >> 16);
}
__device__ __forceinline__ float bh2f(unsigned short h) {
    union { unsigned u; float f; } v; v.u = ((unsigned)h) << 16; return v.f;
}
__device__ __forceinline__ float fast_tanh(float x) {
    float ax = fabsf(x);
    float t  = __expf(-2.0f * ax);
    float r  = (1.0f - t) * __builtin_amdgcn_rcpf(1.0f + t);
    return copysignf(r, x);
}

// wsu layout per type (ushort offsets):
// 0      WT0h [128j][64k]   8192   (fwd L0 hi)     8192 WT0l
// 16384  WT1h [128j][128k] 16384   32768 WT1l
// 49152  WT2h             16384    65536 WT2l
// 81920  WRM2 [128i][128j] 16384   (bwd hi only)
// 98304  WRM1             16384
// 114688 WRM0 [64f][128j]  8192

// ------------------------------------------------ prep: repack + sort -----
__global__ __launch_bounds__(256) void prep_kernel(
    const int* __restrict__ itype,
    const float* __restrict__ W0, const float* __restrict__ W1,
    const float* __restrict__ W2,
    int* __restrict__ order, unsigned short* __restrict__ wsu)
{
    const int blk = blockIdx.x;
    const int t = threadIdx.x;

    if (blk < 20) {
        __shared__ float tile[64][65];
        int ty = blk / 10, m = blk - ty * 10;
        int mat, jt, kt;
        if (m < 2)      { mat = 0; jt = m;            kt = 0; }
        else if (m < 6) { mat = 1; jt = (m - 2) >> 1; kt = (m - 2) & 1; }
        else            { mat = 2; jt = (m - 6) >> 1; kt = (m - 6) & 1; }
        const float* src = (mat == 0) ? W0 + ty * 5000
                          : (mat == 1) ? W1 + ty * 10000 : W2 + ty * 10000;
        const int Krows = (mat == 0) ? 50 : 100;
        const int Ck    = (mat == 0) ? 64 : 128;
        const int dH = ty * TYW + ((mat == 0) ? 0 : (mat == 1) ? 16384 : 49152);
        const int dL = dH + ((mat == 0) ? 8192 : 16384);
        const int j0 = jt * 64, k0 = kt * 64;
        const int rr0 = t >> 6, l = t & 63;
        #pragma unroll
        for (int i = 0; i < 16; ++i) {
            int rr = rr0 + 4 * i;
            int k = k0 + rr, j = j0 + l;
            tile[rr][l] = (k < Krows && j < 100) ? src[k * 100 + j] : 0.0f;
        }
        __syncthreads();
        #pragma unroll
        for (int i = 0; i < 16; ++i) {
            int jj = rr0 + 4 * i;
            float v = tile[l][jj];
            unsigned short h = f2bh(v);
            wsu[dH + (j0 + jj) * Ck + k0 + l] = h;
            wsu[dL + (j0 + jj) * Ck + k0 + l] = f2bh(v - bh2f(h));
        }
        return;
    }
    if (blk < 340) {
        int e = (blk - 20) * 256 + t;          // < 81920
        int ty = e / 40960;
        int r  = e - ty * 40960;
        float v = 0.0f; int dst;
        if (r < 16384) {            // WRM2
            int i = r >> 7, j = r & 127;
            if (i < 100 && j < 100) v = W2[ty * 10000 + i * 100 + j];
            dst = ty * TYW + 81920 + r;
        } else if (r < 32768) {     // WRM1
            int r2 = r - 16384; int i = r2 >> 7, j = r2 & 127;
            if (i < 100 && j < 100) v = W1[ty * 10000 + i * 100 + j];
            dst = ty * TYW + 98304 + r2;
        } else {                    // WRM0
            int r2 = r - 32768; int f = r2 >> 7, j = r2 & 127;
            if (f < 50 && j < 100) v = W0[ty * 5000 + f * 100 + j];
            dst = ty * TYW + 114688 + r2;
        }
        wsu[dst] = f2bh(v);
        return;
    }
    // sort: type partition, pad each segment to ATB
    __shared__ int scan[256];
    for (int i = t; i < ORDER_LEN; i += 256) order[i] = -1;
    int tyv[16]; int c0 = 0;
    #pragma unroll
    for (int k = 0; k < 16; ++k) {
        int tt = (itype[t * 16 + k] == 8) ? 1 : 0;
        tyv[k] = tt; c0 += 1 - tt;
    }
    scan[t] = c0;
    __syncthreads();
    for (int off = 1; off < 256; off <<= 1) {
        int v = scan[t];
        int add = (t >= off) ? scan[t - off] : 0;
        __syncthreads();
        scan[t] = v + add;
        __syncthreads();
    }
    int total0 = scan[255];
    int ex0 = scan[t] - c0;
    int ex1 = 16 * t - ex0;
    int pad0 = (total0 + (ATB - 1)) & ~(ATB - 1);
    int p0 = ex0, p1 = pad0 + ex1;
    #pragma unroll
    for (int k = 0; k < 16; ++k) {
        int idx = t * 16 + k;
        if (tyv[k] == 0) order[p0++] = idx; else order[p1++] = idx;
    }
}

// ------------------------- feat: packed float2 (r, +/-cw), b128 reads ----
__global__ __launch_bounds__(128) void feat_kernel(
    const int* __restrict__ itype, const int* __restrict__ nlist,
    const float* __restrict__ dR, float* __restrict__ featp)
{
    const int atom = blockIdx.x;
    const int b = atom >> 10;
    const int t = threadIdx.x;

    __shared__ float4 rc4[50];
    __shared__ float partial[64];

    if (t < Mn) {
        float4 qv = ((const float4*)dR)[(size_t)atom * Mn + t];
        float r = qv.x;
        int v = nlist[(size_t)atom * Mn + t];
        float cws = 0.0f;
        if (v > 0 && r > 0.0f && r < 6.0f) {
            float cw = 0.5f * __cosf(PIc * r) + 0.5f;
            cws = (itype[b * Nn + (v - 1)] == 8) ? -cw : cw;
        }
        ((float2*)rc4)[t] = make_float2(r, cws);
    }
    __syncthreads();

    const int w = t >> 6, l = t & 63;
    const int tt = l / NB;
    const float rk = 0.5f + (l - tt * NB) * RSTEP;
    float acc = 0.0f;
    #pragma unroll
    for (int i = 0; i < 25; ++i) {
        float4 pr = rc4[w * 25 + i];
        float d0 = pr.x - rk, d1 = pr.z - rk;
        float c0 = tt ? fmaxf(-pr.y, 0.0f) : fmaxf(pr.y, 0.0f);
        float c1 = tt ? fmaxf(-pr.w, 0.0f) : fmaxf(pr.w, 0.0f);
        acc += __expf(-d0 * d0) * c0 + __expf(-d1 * d1) * c1;
    }
    if (w == 1) partial[l] = acc;
    __syncthreads();
    if (w == 0) {
        float tot = (l < FEAT) ? (acc + partial[l]) : 0.0f;
        featp[(size_t)atom * 64 + l] = tot;
    }
}

// ----------------------------------------------------------------- mlp ----
// 512 thr = 8 waves, 16 REAL type-pure atoms. Each wave owns ONE 16-col
// n-tile; B double-buffered in registers with cross-phase prefetch.
#define ISSUE(RH, RL, OFFU, OFFL, RW, NKT, HASLO, COND)                       \
    if (COND) {                                                               \
        int jj_ = c + 16 * w;                                                 \
        _Pragma("unroll")                                                     \
        for (int kt = 0; kt < (NKT); ++kt) {                                  \
            int boff_ = jj_ * (RW) + kt * 32 + q * 8;                         \
            RH[kt] = *(const bf16x8*)(wb + (OFFU) + boff_);                   \
            if (HASLO) RL[kt] = *(const bf16x8*)(wb + (OFFL) + boff_);        \
        }                                                                     \
    }

#define GEMM_R(ABUF, RH, RL, NKT, HASLO)                                      \
    {                                                                         \
        acc = (f32x4){0,0,0,0}; accl = (f32x4){0,0,0,0};                      \
        _Pragma("unroll")                                                     \
        for (int kt = 0; kt < (NKT); ++kt) {                                  \
            int gk = kt * 4 + q;                                              \
            bf16x8 af = *(const bf16x8*)&aA[ABUF][(c << 7) | ((gk ^ (c & 7)) << 3)]; \
            acc = __builtin_amdgcn_mfma_f32_16x16x32_bf16(af, RH[kt], acc, 0, 0, 0); \
            if (HASLO) accl = __builtin_amdgcn_mfma_f32_16x16x32_bf16(af, RL[kt], accl, 0, 0, 0); \
        }                                                                     \
    }

#define WRACT(BUF, J, A, X)                                                   \
    aA[BUF][((A) << 7) | ((((J) >> 3) ^ ((A) & 7)) << 3) | ((J) & 7)] = f2bh(X)

__global__ __launch_bounds__(512) void mlp_kernel(
    const float* __restrict__ featp, const int* __restrict__ itype,
    const int* __restrict__ order, const unsigned short* __restrict__ wsu,
    const float* __restrict__ B0, const float* __restrict__ B1,
    const float* __restrict__ B2, const float* __restrict__ W3,
    const float* __restrict__ B3,
    float* __restrict__ Ei, float* __restrict__ dE)
{
    const int t = threadIdx.x;
    const int w = t >> 6;
    const int lane = t & 63;
    const int c = lane & 15, q = lane >> 4;

    __shared__ unsigned short aA[2][2048];
    __shared__ float fshf[16][52];
    __shared__ float dx1s[16][112];
    __shared__ float biasS[4][128];
    __shared__ float eip[8][16];
    __shared__ int aid[16];

    if (t < 16) aid[t] = order[blockIdx.x * ATB + t];
    __syncthreads();
    int first = -1;
    #pragma unroll
    for (int a = 0; a < ATB; ++a) { int v = aid[a]; if (first < 0 && v >= 0) first = v; }
    if (first < 0) return;
    const int ty = (itype[first] == 8) ? 1 : 0;
    const unsigned short* wb = wsu + (size_t)ty * TYW;

    bf16x8 bh0[4], bl0[4], bh1[4], bl1[4];
    f32x4 acc, accl;
    float xr[4], h0r[4], h1r[4], h2r[4], dxr[4];

    ISSUE(bh0, bl0, 0, 8192, 64, 2, 1, true);
    if (t < 128) {
        const int srow = t >> 3, sg = t & 7;
        int v = aid[srow];
        float4 fa = {0,0,0,0}, fb = {0,0,0,0};
        if (v >= 0) {
            const float4* fp = (const float4*)(featp + (size_t)v * 64 + sg * 8);
            fa = fp[0]; fb = fp[1];
        }
        U16x8 pk;
        pk.u[0]=f2bh(fa.x); pk.u[1]=f2bh(fa.y); pk.u[2]=f2bh(fa.z); pk.u[3]=f2bh(fa.w);
        pk.u[4]=f2bh(fb.x); pk.u[5]=f2bh(fb.y); pk.u[6]=f2bh(fb.z); pk.u[7]=f2bh(fb.w);
        *(uint4*)&aA[0][(srow << 7) | ((sg ^ (srow & 7)) << 3)] = pk.q;
        int cbase = sg * 8;
        if (cbase < 52) {
            float vals[8] = {fa.x,fa.y,fa.z,fa.w,fb.x,fb.y,fb.z,fb.w};
            #pragma unroll
            for (int j7 = 0; j7 < 8; ++j7)
                if (cbase + j7 < 52) fshf[srow][cbase + j7] = vals[j7];
        }
    }
    if (t < 512) {
        int row = t >> 7, col = t & 127;
        const float* s = (row == 0) ? B0 : (row == 1) ? B1 : (row == 2) ? B2 : W3;
        biasS[row][col] = (col < 100) ? s[ty * 100 + col] : 0.0f;
    }
    __syncthreads();

    // P0
    ISSUE(bh1, bl1, 16384, 32768, 128, 4, 1, true);
    GEMM_R(0, bh0, bl0, 2, 1);
    {
        int j = c + 16 * w;
        float bj = biasS[0][j];
        #pragma unroll
        for (int r = 0; r < 4; ++r) {
            int a = q * 4 + r;
            float z = acc[r] + accl[r] + bj;
            float h = 0.f, x = 0.f;
            if (j < 100) { h = fast_tanh(z); x = h + fshf[a][(j < 50) ? j : j - 50]; }
            h0r[r] = h; xr[r] = x;
            WRACT(1, j, a, x);
        }
    }
    __syncthreads();

    // P1
    ISSUE(bh0, bl0, 49152, 65536, 128, 4, 1, true);
    GEMM_R(1, bh1, bl1, 4, 1);
    {
        int j = c + 16 * w;
        float bj = biasS[1][j];
        #pragma unroll
        for (int r = 0; r < 4; ++r) {
            int a = q * 4 + r;
            float z = acc[r] + accl[r] + bj;
            float h = (j < 100) ? fast_tanh(z) : 0.f;
            float x = (j < 100) ? (h + xr[r]) : 0.f;
            h1r[r] = h; xr[r] = x;
            WRACT(0, j, a, x);
        }
    }
    __syncthreads();

    // P2
    ISSUE(bh1, bl1, 81920, 0, 128, 4, 0, true);
    GEMM_R(0, bh0, bl0, 4, 1);
    {
        int j = c + 16 * w;
        float bj = biasS[2][j];
        float wv = biasS[3][j];
        float p4v[4];
        #pragma unroll
        for (int r = 0; r < 4; ++r) {
            float z = acc[r] + accl[r] + bj;
            float h = (j < 100) ? fast_tanh(z) : 0.f;
            h2r[r] = h;
            xr[r] = (j < 100) ? (h + xr[r]) : 0.f;
            p4v[r] = xr[r] * wv;
        }
        #pragma unroll
        for (int off = 1; off < 16; off <<= 1) {
            #pragma unroll
            for (int r = 0; r < 4; ++r) p4v[r] += __shfl_xor(p4v[r], off);
        }
        if (c == 0) {
            #pragma unroll
            for (int r = 0; r < 4; ++r) eip[w][q * 4 + r] = p4v[r];
        }
        #pragma unroll
        for (int r = 0; r < 4; ++r) {
            int a = q * 4 + r;
            float d = wv * (1.0f - h2r[r] * h2r[r]);
            WRACT(1, j, a, d);
        }
    }
    __syncthreads();
    if (t < 16) {
        int v = aid[t];
        if (v >= 0) {
            float e = B3[ty];
            #pragma unroll
            for (int ww = 0; ww < 8; ++ww) e += eip[ww][t];
            Ei[v] = e;
        }
    }

    // P3
    ISSUE(bh0, bl0, 98304, 0, 128, 4, 0, true);
    GEMM_R(1, bh1, bl1, 4, 0);
    {
        int i = c + 16 * w;
        float w3i = biasS[3][i];
        #pragma unroll
        for (int r = 0; r < 4; ++r) {
            int a = q * 4 + r;
            float dx2 = acc[r] + w3i;
            dxr[r] = dx2;
            float d = dx2 * (1.0f - h1r[r] * h1r[r]);
            WRACT(0, i, a, d);
        }
    }
    __syncthreads();

    // P4
    ISSUE(bh1, bl1, 114688, 0, 128, 4, 0, (w < 4));
    GEMM_R(0, bh0, bl0, 4, 0);
    {
        int i = c + 16 * w;
        #pragma unroll
        for (int r = 0; r < 4; ++r) {
            int a = q * 4 + r;
            float dx1 = dxr[r] + acc[r];
            if (i < 112) dx1s[a][i] = dx1;
            float d = dx1 * (1.0f - h0r[r] * h0r[r]);
            WRACT(1, i, a, d);
        }
    }
    __syncthreads();

    // P5
    if (w < 4) {
        GEMM_R(1, bh1, bl1, 4, 0);
        int f = c + 16 * w;
        if (f < 50) {
            #pragma unroll
            for (int r = 0; r < 4; ++r) {
                int a = q * 4 + r;
                int v = aid[a];
                if (v >= 0) dE[(size_t)v * FEAT + f] = acc[r] + dx1s[a][f] + dx1s[a][f + 50];
            }
        }
    }
}

// ------------------- force: wave-owns-center (no same-address storm) ------
__global__ __launch_bounds__(FTHREADS) void force_kernel(
    const int* __restrict__ itype, const int* __restrict__ nlist,
    const float* __restrict__ dR, const float* __restrict__ dE,
    float* __restrict__ partial)
{
    const int blk = blockIdx.x;
    const int b = blk / GPB;
    const int g = blk - b * GPB;
    const int t = threadIdx.x;
    const int w = t >> 6, lane = t & 63;

    __shared__ float acc[(Nn + 1) * 3];
    __shared__ float desh[CPG][FEAT];

    for (int idx = t; idx < (Nn + 1) * 3; idx += FTHREADS) acc[idx] = 0.0f;
    for (int idx = t; idx < CPG * FEAT; idx += FTHREADS)
        ((float*)desh)[idx] = dE[((size_t)(b * Nn) + g * CPG) * FEAT + idx];
    __syncthreads();

    for (int cc = w; cc < CPG; cc += 8) {          // each wave owns one center
        const int n = g * CPG + cc;
        float cfx = 0.f, cfy = 0.f, cfz = 0.f;
        #pragma unroll
        for (int mi = 0; mi < 2; ++mi) {
            int m = lane + mi * 64;
            if (m < Mn) {
                size_t pair = (size_t)(b * Nn + n) * Mn + m;
                float4 qv = ((const float4*)dR)[pair];
                int v = nlist[pair];
                if (v > 0) {
                    float r = qv.x;
                    if (r > 0.0f && r < 6.0f) {
                        int tt = (itype[b * Nn + v - 1] == 8) ? 1 : 0;
                        float cw  = 0.5f * __cosf(PIc * r) + 0.5f;
                        float dcw = -0.5f * PIc * __sinf(PIc * r);
                        float s = 0.0f;
                        const float* de = &desh[cc][tt * NB];
                        #pragma unroll
                        for (int k = 0; k < NB; ++k) {
                            float d = r - (0.5f + k * RSTEP);
                            float e = __expf(-d * d);
                            s += de[k] * e * __builtin_fmaf(-2.0f * cw, d, dcw);
                        }
                        float inv = 1.0f / r;
                        float fx = s * qv.y * inv, fy = s * qv.z * inv, fz = s * qv.w * inv;
                        // neighbor side: random distinct addresses -> parallel
                        atomicAdd(&acc[v * 3 + 0], fx);
                        atomicAdd(&acc[v * 3 + 1], fy);
                        atomicAdd(&acc[v * 3 + 2], fz);
                        // center side: accumulate in registers
                        cfx += fx; cfy += fy; cfz += fz;
                    }
                }
            }
        }
        // one wave-reduce + ONE atomic per center (was ~300 same-address ops)
        #pragma unroll
        for (int off = 32; off > 0; off >>= 1) {
            cfx += __shfl_xor(cfx, off);
            cfy += __shfl_xor(cfy, off);
            cfz += __shfl_xor(cfz, off);
        }
        if (lane == 0) {
            atomicAdd(&acc[(n + 1) * 3 + 0], -cfx);
            atomicAdd(&acc[(n + 1) * 3 + 1], -cfy);
            atomicAdd(&acc[(n + 1) * 3 + 2], -cfz);
        }
    }
    __syncthreads();

    float* pout = partial + (size_t)blk * ((Nn + 1) * 3);
    for (int idx = t; idx < (Nn + 1) * 3; idx += FTHREADS) pout[idx] = acc[idx];
}

// ----------------------------------------------------- freduce (+etot) ----
__global__ __launch_bounds__(256) void freduce_kernel(
    const float* __restrict__ partial, const float* __restrict__ Ei,
    float* __restrict__ Force, float* __restrict__ Etot)
{
    if (blockIdx.x == 48) {   // etot
        const int t = threadIdx.x;
        __shared__ float red[256];
        for (int b = 0; b < Bn; ++b) {
            float s = 0.0f;
            for (int i = t; i < Nn; i += 256) s += Ei[b * Nn + i];
            red[t] = s;
            __syncthreads();
            for (int st = 128; st > 0; st >>= 1) {
                if (t < st) red[t] += red[t + st];
                __syncthreads();
            }
            if (t == 0) Etot[b] = red[0];
            __syncthreads();
        }
        return;
    }
    int idx = blockIdx.x * 256 + threadIdx.x;
    if (idx >= Bn * Nn * 3) return;
    int b = idx / (Nn * 3);
    int r = idx - b * (Nn * 3);
    int i = r / 3, ch = r - i * 3;
    float s = 0.0f;
    for (int g = 0; g < GPB; ++g)
        s += partial[((size_t)(b * GPB + g)) * ((Nn + 1) * 3) + (size_t)(i + 1) * 3 + ch];
    Force[idx] = s;
}

// -------------------------------------------------------------- launch ----
extern "C" void kernel_launch(void* const* d_in, const int* in_sizes, int n_in,
                              void* d_out, int out_size, void* d_ws, size_t ws_size,
                              hipStream_t stream)
{
    const int*   itype = (const int*)d_in[0];
    const int*   nlist = (const int*)d_in[1];
    const float* dR    = (const float*)d_in[2];
    const float* W0 = (const float*)d_in[3];  const float* B0 = (const float*)d_in[4];
    const float* W1 = (const float*)d_in[5];  const float* B1 = (const float*)d_in[6];
    const float* W2 = (const float*)d_in[7];  const float* B2 = (const float*)d_in[8];
    const float* W3 = (const float*)d_in[9];  const float* B3 = (const float*)d_in[10];

    float* out   = (float*)d_out;
    float* Etot  = out;                    // [B,1]
    float* Ei    = out + Bn;               // [B,N,1]
    float* Force = out + Bn + Bn * Nn;     // [B,N,3]

    float* featp   = (float*)d_ws;                              // NATOMS*64 f32
    float* dEp     = featp + (size_t)NATOMS * 64;               // NATOMS*50 f32
    float* partial = dEp + (size_t)NATOMS * FEAT;               // Bn*GPB*(Nn+1)*3
    int*   order   = (int*)(partial + (size_t)Bn * GPB * (Nn + 1) * 3);
    unsigned short* wsu = (unsigned short*)(order + ORDER_LEN); // 2*TYW ushorts

    prep_kernel   <<<341, 256, 0, stream>>>(itype, W0, W1, W2, order, wsu);
    feat_kernel   <<<NATOMS, 128, 0, stream>>>(itype, nlist, dR, featp);
    mlp_kernel    <<<MLP_BLOCKS, 512, 0, stream>>>(featp, itype, order, wsu,
                                                   B0, B1, B2, W3, B3, Ei, dEp);
    force_kernel  <<<Bn * GPB, FTHREADS, 0, stream>>>(itype, nlist, dR, dEp, partial);
    freduce_kernel<<<49, 256, 0, stream>>>(partial, Ei, Force, Etot);
}

// Round 16
// 51.628 us; speedup vs baseline: 3.1333x; 1.0498x over previous
//
#include <hip/hip_runtime.h>

#define Bn   4
#define Nn   1024
#define Mn   100
#define NB   25
#define FEAT 50
#define PIc  3.1415926f
#define RSTEP (5.5f / 24.0f)

#define ATB  16                         // atoms per MLP block (all real)
#define NATOMS (Bn * Nn)
#define ORDER_LEN (NATOMS + ATB)        // 4112
#define MLP_BLOCKS (ORDER_LEN / ATB)    // 257
#define TYW  122880                     // ushorts per type in wsu
#define PREP_BLKS 341                   // prep roles inside stage1

#define GPB  64
#define CPG  16
#define FTHREADS 512

typedef __attribute__((ext_vector_type(8))) short bf16x8;
typedef __attribute__((ext_vector_type(4))) float f32x4;

union U16x8 { unsigned short u[8]; bf16x8 v; uint4 q; };

__device__ __forceinline__ unsigned short f2bh(float x) {
    union { float f; unsigned u; } v; v.f = x;
    unsigned r = v.u + 0x7fffu + ((v.u >> 16) & 1u);
    return (unsigned short)(r >> 16);
}
__device__ __forceinline__ float bh2f(unsigned short h) {
    union { unsigned u; float f; } v; v.u = ((unsigned)h) << 16; return v.f;
}
__device__ __forceinline__ float fast_tanh(float x) {
    float ax = fabsf(x);
    float t  = __expf(-2.0f * ax);
    float r  = (1.0f - t) * __builtin_amdgcn_rcpf(1.0f + t);
    return copysignf(r, x);
}

// wsu layout per type (ushort offsets):
// 0      WT0h [128j][64k]   8192   (fwd L0 hi)     8192 WT0l
// 16384  WT1h [128j][128k] 16384   32768 WT1l
// 49152  WT2h             16384    65536 WT2l
// 81920  WRM2 [128i][128j] 16384   (bwd hi only)
// 98304  WRM1             16384
// 114688 WRM0 [64f][128j]  8192

// ---------------- stage1: prep (repack+sort) + feat, independent roles ----
__global__ __launch_bounds__(256) void stage1_kernel(
    const int* __restrict__ itype, const int* __restrict__ nlist,
    const float* __restrict__ dR,
    const float* __restrict__ W0, const float* __restrict__ W1,
    const float* __restrict__ W2,
    int* __restrict__ order, unsigned short* __restrict__ wsu,
    float* __restrict__ featp)
{
    const int blk = blockIdx.x;
    const int t = threadIdx.x;

    __shared__ float tile[64][65];      // prep transpose
    __shared__ int scan[256];           // sort
    __shared__ float4 rc4[50];          // feat pairs
    __shared__ float fpartial[64];      // feat cross-wave

    if (blk < 20) {
        int ty = blk / 10, m = blk - ty * 10;
        int mat, jt, kt;
        if (m < 2)      { mat = 0; jt = m;            kt = 0; }
        else if (m < 6) { mat = 1; jt = (m - 2) >> 1; kt = (m - 2) & 1; }
        else            { mat = 2; jt = (m - 6) >> 1; kt = (m - 6) & 1; }
        const float* src = (mat == 0) ? W0 + ty * 5000
                          : (mat == 1) ? W1 + ty * 10000 : W2 + ty * 10000;
        const int Krows = (mat == 0) ? 50 : 100;
        const int Ck    = (mat == 0) ? 64 : 128;
        const int dH = ty * TYW + ((mat == 0) ? 0 : (mat == 1) ? 16384 : 49152);
        const int dL = dH + ((mat == 0) ? 8192 : 16384);
        const int j0 = jt * 64, k0 = kt * 64;
        const int rr0 = t >> 6, l = t & 63;
        #pragma unroll
        for (int i = 0; i < 16; ++i) {
            int rr = rr0 + 4 * i;
            int k = k0 + rr, j = j0 + l;
            tile[rr][l] = (k < Krows && j < 100) ? src[k * 100 + j] : 0.0f;
        }
        __syncthreads();
        #pragma unroll
        for (int i = 0; i < 16; ++i) {
            int jj = rr0 + 4 * i;
            float v = tile[l][jj];
            unsigned short h = f2bh(v);
            wsu[dH + (j0 + jj) * Ck + k0 + l] = h;
            wsu[dL + (j0 + jj) * Ck + k0 + l] = f2bh(v - bh2f(h));
        }
        return;
    }
    if (blk < 340) {
        int e = (blk - 20) * 256 + t;          // < 81920
        int ty = e / 40960;
        int r  = e - ty * 40960;
        float v = 0.0f; int dst;
        if (r < 16384) {            // WRM2
            int i = r >> 7, j = r & 127;
            if (i < 100 && j < 100) v = W2[ty * 10000 + i * 100 + j];
            dst = ty * TYW + 81920 + r;
        } else if (r < 32768) {     // WRM1
            int r2 = r - 16384; int i = r2 >> 7, j = r2 & 127;
            if (i < 100 && j < 100) v = W1[ty * 10000 + i * 100 + j];
            dst = ty * TYW + 98304 + r2;
        } else {                    // WRM0
            int r2 = r - 32768; int f = r2 >> 7, j = r2 & 127;
            if (f < 50 && j < 100) v = W0[ty * 5000 + f * 100 + j];
            dst = ty * TYW + 114688 + r2;
        }
        wsu[dst] = f2bh(v);
        return;
    }
    if (blk == 340) {
        // sort: type partition, pad each segment to ATB
        for (int i = t; i < ORDER_LEN; i += 256) order[i] = -1;
        int tyv[16]; int c0 = 0;
        #pragma unroll
        for (int k = 0; k < 16; ++k) {
            int tt = (itype[t * 16 + k] == 8) ? 1 : 0;
            tyv[k] = tt; c0 += 1 - tt;
        }
        scan[t] = c0;
        __syncthreads();
        for (int off = 1; off < 256; off <<= 1) {
            int v = scan[t];
            int add = (t >= off) ? scan[t - off] : 0;
            __syncthreads();
            scan[t] = v + add;
            __syncthreads();
        }
        int total0 = scan[255];
        int ex0 = scan[t] - c0;
        int ex1 = 16 * t - ex0;
        int pad0 = (total0 + (ATB - 1)) & ~(ATB - 1);
        int p0 = ex0, p1 = pad0 + ex1;
        #pragma unroll
        for (int k = 0; k < 16; ++k) {
            int idx = t * 16 + k;
            if (tyv[k] == 0) order[p0++] = idx; else order[p1++] = idx;
        }
        return;
    }

    // -------- feat role: atom = blk - PREP_BLKS (packed (r, +/-cw)) --------
    const int atom = blk - PREP_BLKS;
    const int b = atom >> 10;

    if (t < Mn) {
        float4 qv = ((const float4*)dR)[(size_t)atom * Mn + t];
        float r = qv.x;
        int v = nlist[(size_t)atom * Mn + t];
        float cws = 0.0f;
        if (v > 0 && r > 0.0f && r < 6.0f) {
            float cw = 0.5f * __cosf(PIc * r) + 0.5f;
            cws = (itype[b * Nn + (v - 1)] == 8) ? -cw : cw;
        }
        ((float2*)rc4)[t] = make_float2(r, cws);
    }
    __syncthreads();

    float acc = 0.0f;
    if (t < 128) {
        const int w = t >> 6, l = t & 63;
        const int tt = l / NB;
        const float rk = 0.5f + (l - tt * NB) * RSTEP;
        #pragma unroll
        for (int i = 0; i < 25; ++i) {
            float4 pr = rc4[w * 25 + i];
            float d0 = pr.x - rk, d1 = pr.z - rk;
            float c0 = tt ? fmaxf(-pr.y, 0.0f) : fmaxf(pr.y, 0.0f);
            float c1 = tt ? fmaxf(-pr.w, 0.0f) : fmaxf(pr.w, 0.0f);
            acc += __expf(-d0 * d0) * c0 + __expf(-d1 * d1) * c1;
        }
        if (w == 1) fpartial[l] = acc;
    }
    __syncthreads();
    if (t < 64)
        featp[(size_t)atom * 64 + t] = (t < FEAT) ? (acc + fpartial[t]) : 0.0f;
}

// ----------------------------------------------------------------- mlp ----
// 512 thr = 8 waves, 16 REAL type-pure atoms. Each wave owns ONE 16-col
// n-tile; B double-buffered in registers with cross-phase prefetch.
#define ISSUE(RH, RL, OFFU, OFFL, RW, NKT, HASLO, COND)                       \
    if (COND) {                                                               \
        int jj_ = c + 16 * w;                                                 \
        _Pragma("unroll")                                                     \
        for (int kt = 0; kt < (NKT); ++kt) {                                  \
            int boff_ = jj_ * (RW) + kt * 32 + q * 8;                         \
            RH[kt] = *(const bf16x8*)(wb + (OFFU) + boff_);                   \
            if (HASLO) RL[kt] = *(const bf16x8*)(wb + (OFFL) + boff_);        \
        }                                                                     \
    }

#define GEMM_R(ABUF, RH, RL, NKT, HASLO)                                      \
    {                                                                         \
        acc = (f32x4){0,0,0,0}; accl = (f32x4){0,0,0,0};                      \
        _Pragma("unroll")                                                     \
        for (int kt = 0; kt < (NKT); ++kt) {                                  \
            int gk = kt * 4 + q;                                              \
            bf16x8 af = *(const bf16x8*)&aA[ABUF][(c << 7) | ((gk ^ (c & 7)) << 3)]; \
            acc = __builtin_amdgcn_mfma_f32_16x16x32_bf16(af, RH[kt], acc, 0, 0, 0); \
            if (HASLO) accl = __builtin_amdgcn_mfma_f32_16x16x32_bf16(af, RL[kt], accl, 0, 0, 0); \
        }                                                                     \
    }

#define WRACT(BUF, J, A, X)                                                   \
    aA[BUF][((A) << 7) | ((((J) >> 3) ^ ((A) & 7)) << 3) | ((J) & 7)] = f2bh(X)

__global__ __launch_bounds__(512) void mlp_kernel(
    const float* __restrict__ featp, const int* __restrict__ itype,
    const int* __restrict__ order, const unsigned short* __restrict__ wsu,
    const float* __restrict__ B0, const float* __restrict__ B1,
    const float* __restrict__ B2, const float* __restrict__ W3,
    const float* __restrict__ B3,
    float* __restrict__ Ei, float* __restrict__ dE)
{
    const int t = threadIdx.x;
    const int w = t >> 6;
    const int lane = t & 63;
    const int c = lane & 15, q = lane >> 4;

    __shared__ unsigned short aA[2][2048];
    __shared__ float fshf[16][52];
    __shared__ float dx1s[16][112];
    __shared__ float biasS[4][128];
    __shared__ float eip[8][16];
    __shared__ int aid[16];

    if (t < 16) aid[t] = order[blockIdx.x * ATB + t];
    __syncthreads();
    int first = -1;
    #pragma unroll
    for (int a = 0; a < ATB; ++a) { int v = aid[a]; if (first < 0 && v >= 0) first = v; }
    if (first < 0) return;
    const int ty = (itype[first] == 8) ? 1 : 0;
    const unsigned short* wb = wsu + (size_t)ty * TYW;

    bf16x8 bh0[4], bl0[4], bh1[4], bl1[4];
    f32x4 acc, accl;
    float xr[4], h0r[4], h1r[4], h2r[4], dxr[4];

    ISSUE(bh0, bl0, 0, 8192, 64, 2, 1, true);
    if (t < 128) {
        const int srow = t >> 3, sg = t & 7;
        int v = aid[srow];
        float4 fa = {0,0,0,0}, fb = {0,0,0,0};
        if (v >= 0) {
            const float4* fp = (const float4*)(featp + (size_t)v * 64 + sg * 8);
            fa = fp[0]; fb = fp[1];
        }
        U16x8 pk;
        pk.u[0]=f2bh(fa.x); pk.u[1]=f2bh(fa.y); pk.u[2]=f2bh(fa.z); pk.u[3]=f2bh(fa.w);
        pk.u[4]=f2bh(fb.x); pk.u[5]=f2bh(fb.y); pk.u[6]=f2bh(fb.z); pk.u[7]=f2bh(fb.w);
        *(uint4*)&aA[0][(srow << 7) | ((sg ^ (srow & 7)) << 3)] = pk.q;
        int cbase = sg * 8;
        if (cbase < 52) {
            float vals[8] = {fa.x,fa.y,fa.z,fa.w,fb.x,fb.y,fb.z,fb.w};
            #pragma unroll
            for (int j7 = 0; j7 < 8; ++j7)
                if (cbase + j7 < 52) fshf[srow][cbase + j7] = vals[j7];
        }
    }
    if (t < 512) {
        int row = t >> 7, col = t & 127;
        const float* s = (row == 0) ? B0 : (row == 1) ? B1 : (row == 2) ? B2 : W3;
        biasS[row][col] = (col < 100) ? s[ty * 100 + col] : 0.0f;
    }
    __syncthreads();

    // P0
    ISSUE(bh1, bl1, 16384, 32768, 128, 4, 1, true);
    GEMM_R(0, bh0, bl0, 2, 1);
    {
        int j = c + 16 * w;
        float bj = biasS[0][j];
        #pragma unroll
        for (int r = 0; r < 4; ++r) {
            int a = q * 4 + r;
            float z = acc[r] + accl[r] + bj;
            float h = 0.f, x = 0.f;
            if (j < 100) { h = fast_tanh(z); x = h + fshf[a][(j < 50) ? j : j - 50]; }
            h0r[r] = h; xr[r] = x;
            WRACT(1, j, a, x);
        }
    }
    __syncthreads();

    // P1
    ISSUE(bh0, bl0, 49152, 65536, 128, 4, 1, true);
    GEMM_R(1, bh1, bl1, 4, 1);
    {
        int j = c + 16 * w;
        float bj = biasS[1][j];
        #pragma unroll
        for (int r = 0; r < 4; ++r) {
            int a = q * 4 + r;
            float z = acc[r] + accl[r] + bj;
            float h = (j < 100) ? fast_tanh(z) : 0.f;
            float x = (j < 100) ? (h + xr[r]) : 0.f;
            h1r[r] = h; xr[r] = x;
            WRACT(0, j, a, x);
        }
    }
    __syncthreads();

    // P2
    ISSUE(bh1, bl1, 81920, 0, 128, 4, 0, true);
    GEMM_R(0, bh0, bl0, 4, 1);
    {
        int j = c + 16 * w;
        float bj = biasS[2][j];
        float wv = biasS[3][j];
        float p4v[4];
        #pragma unroll
        for (int r = 0; r < 4; ++r) {
            float z = acc[r] + accl[r] + bj;
            float h = (j < 100) ? fast_tanh(z) : 0.f;
            h2r[r] = h;
            xr[r] = (j < 100) ? (h + xr[r]) : 0.f;
            p4v[r] = xr[r] * wv;
        }
        #pragma unroll
        for (int off = 1; off < 16; off <<= 1) {
            #pragma unroll
            for (int r = 0; r < 4; ++r) p4v[r] += __shfl_xor(p4v[r], off);
        }
        if (c == 0) {
            #pragma unroll
            for (int r = 0; r < 4; ++r) eip[w][q * 4 + r] = p4v[r];
        }
        #pragma unroll
        for (int r = 0; r < 4; ++r) {
            int a = q * 4 + r;
            float d = wv * (1.0f - h2r[r] * h2r[r]);
            WRACT(1, j, a, d);
        }
    }
    __syncthreads();
    if (t < 16) {
        int v = aid[t];
        if (v >= 0) {
            float e = B3[ty];
            #pragma unroll
            for (int ww = 0; ww < 8; ++ww) e += eip[ww][t];
            Ei[v] = e;
        }
    }

    // P3
    ISSUE(bh0, bl0, 98304, 0, 128, 4, 0, true);
    GEMM_R(1, bh1, bl1, 4, 0);
    {
        int i = c + 16 * w;
        float w3i = biasS[3][i];
        #pragma unroll
        for (int r = 0; r < 4; ++r) {
            int a = q * 4 + r;
            float dx2 = acc[r] + w3i;
            dxr[r] = dx2;
            float d = dx2 * (1.0f - h1r[r] * h1r[r]);
            WRACT(0, i, a, d);
        }
    }
    __syncthreads();

    // P4
    ISSUE(bh1, bl1, 114688, 0, 128, 4, 0, (w < 4));
    GEMM_R(0, bh0, bl0, 4, 0);
    {
        int i = c + 16 * w;
        #pragma unroll
        for (int r = 0; r < 4; ++r) {
            int a = q * 4 + r;
            float dx1 = dxr[r] + acc[r];
            if (i < 112) dx1s[a][i] = dx1;
            float d = dx1 * (1.0f - h0r[r] * h0r[r]);
            WRACT(1, i, a, d);
        }
    }
    __syncthreads();

    // P5
    if (w < 4) {
        GEMM_R(1, bh1, bl1, 4, 0);
        int f = c + 16 * w;
        if (f < 50) {
            #pragma unroll
            for (int r = 0; r < 4; ++r) {
                int a = q * 4 + r;
                int v = aid[a];
                if (v >= 0) dE[(size_t)v * FEAT + f] = acc[r] + dx1s[a][f] + dx1s[a][f + 50];
            }
        }
    }
}

// ------------------- force: wave-owns-center, loads issued up-front -------
__global__ __launch_bounds__(FTHREADS) void force_kernel(
    const int* __restrict__ itype, const int* __restrict__ nlist,
    const float* __restrict__ dR, const float* __restrict__ dE,
    float* __restrict__ partial)
{
    const int blk = blockIdx.x;
    const int b = blk / GPB;
    const int g = blk - b * GPB;
    const int t = threadIdx.x;
    const int w = t >> 6, lane = t & 63;

    __shared__ float acc[(Nn + 1) * 3];
    __shared__ float desh[CPG][FEAT];

    for (int idx = t; idx < (Nn + 1) * 3; idx += FTHREADS) acc[idx] = 0.0f;
    for (int idx = t; idx < CPG * FEAT; idx += FTHREADS)
        ((float*)desh)[idx] = dE[((size_t)(b * Nn) + g * CPG) * FEAT + idx];
    __syncthreads();

    for (int cc = w; cc < CPG; cc += 8) {          // each wave owns one center
        const int n = g * CPG + cc;
        const size_t pairbase = (size_t)(b * Nn + n) * Mn;

        // issue BOTH rounds' loads up-front (one latency wait, not two)
        const int m1 = lane + 64;
        float4 qv0 = ((const float4*)dR)[pairbase + lane];
        int    v0  = nlist[pairbase + lane];
        float4 qv1 = make_float4(0.f, 0.f, 0.f, 0.f);
        int    v1  = 0;
        if (m1 < Mn) {
            qv1 = ((const float4*)dR)[pairbase + m1];
            v1  = nlist[pairbase + m1];
        }

        float cfx = 0.f, cfy = 0.f, cfz = 0.f;
        #pragma unroll
        for (int mi = 0; mi < 2; ++mi) {
            float4 qv = mi ? qv1 : qv0;
            int v = mi ? v1 : v0;
            if (v > 0) {
                float r = qv.x;
                if (r > 0.0f && r < 6.0f) {
                    int tt = (itype[b * Nn + v - 1] == 8) ? 1 : 0;
                    float cw  = 0.5f * __cosf(PIc * r) + 0.5f;
                    float dcw = -0.5f * PIc * __sinf(PIc * r);
                    float s = 0.0f;
                    const float* de = &desh[cc][tt * NB];
                    #pragma unroll
                    for (int k = 0; k < NB; ++k) {
                        float d = r - (0.5f + k * RSTEP);
                        float e = __expf(-d * d);
                        s += de[k] * e * __builtin_fmaf(-2.0f * cw, d, dcw);
                    }
                    float inv = 1.0f / r;
                    float fx = s * qv.y * inv, fy = s * qv.z * inv, fz = s * qv.w * inv;
                    atomicAdd(&acc[v * 3 + 0], fx);
                    atomicAdd(&acc[v * 3 + 1], fy);
                    atomicAdd(&acc[v * 3 + 2], fz);
                    cfx += fx; cfy += fy; cfz += fz;
                }
            }
        }
        #pragma unroll
        for (int off = 32; off > 0; off >>= 1) {
            cfx += __shfl_xor(cfx, off);
            cfy += __shfl_xor(cfy, off);
            cfz += __shfl_xor(cfz, off);
        }
        if (lane == 0) {
            atomicAdd(&acc[(n + 1) * 3 + 0], -cfx);
            atomicAdd(&acc[(n + 1) * 3 + 1], -cfy);
            atomicAdd(&acc[(n + 1) * 3 + 2], -cfz);
        }
    }
    __syncthreads();

    float* pout = partial + (size_t)blk * ((Nn + 1) * 3);
    for (int idx = t; idx < (Nn + 1) * 3; idx += FTHREADS) pout[idx] = acc[idx];
}

// ----------------------------------------------------- freduce (+etot) ----
__global__ __launch_bounds__(256) void freduce_kernel(
    const float* __restrict__ partial, const float* __restrict__ Ei,
    float* __restrict__ Force, float* __restrict__ Etot)
{
    if (blockIdx.x == 48) {   // etot
        const int t = threadIdx.x;
        __shared__ float red[256];
        for (int b = 0; b < Bn; ++b) {
            float s = 0.0f;
            for (int i = t; i < Nn; i += 256) s += Ei[b * Nn + i];
            red[t] = s;
            __syncthreads();
            for (int st = 128; st > 0; st >>= 1) {
                if (t < st) red[t] += red[t + st];
                __syncthreads();
            }
            if (t == 0) Etot[b] = red[0];
            __syncthreads();
        }
        return;
    }
    int idx = blockIdx.x * 256 + threadIdx.x;
    if (idx >= Bn * Nn * 3) return;
    int b = idx / (Nn * 3);
    int r = idx - b * (Nn * 3);
    int i = r / 3, ch = r - i * 3;
    float s = 0.0f;
    for (int g = 0; g < GPB; ++g)
        s += partial[((size_t)(b * GPB + g)) * ((Nn + 1) * 3) + (size_t)(i + 1) * 3 + ch];
    Force[idx] = s;
}

// -------------------------------------------------------------- launch ----
extern "C" void kernel_launch(void* const* d_in, const int* in_sizes, int n_in,
                              void* d_out, int out_size, void* d_ws, size_t ws_size,
                              hipStream_t stream)
{
    const int*   itype = (const int*)d_in[0];
    const int*   nlist = (const int*)d_in[1];
    const float* dR    = (const float*)d_in[2];
    const float* W0 = (const float*)d_in[3];  const float* B0 = (const float*)d_in[4];
    const float* W1 = (const float*)d_in[5];  const float* B1 = (const float*)d_in[6];
    const float* W2 = (const float*)d_in[7];  const float* B2 = (const float*)d_in[8];
    const float* W3 = (const float*)d_in[9];  const float* B3 = (const float*)d_in[10];

    float* out   = (float*)d_out;
    float* Etot  = out;                    // [B,1]
    float* Ei    = out + Bn;               // [B,N,1]
    float* Force = out + Bn + Bn * Nn;     // [B,N,3]

    float* featp   = (float*)d_ws;                              // NATOMS*64 f32
    float* dEp     = featp + (size_t)NATOMS * 64;               // NATOMS*50 f32
    float* partial = dEp + (size_t)NATOMS * FEAT;               // Bn*GPB*(Nn+1)*3
    int*   order   = (int*)(partial + (size_t)Bn * GPB * (Nn + 1) * 3);
    unsigned short* wsu = (unsigned short*)(order + ORDER_LEN); // 2*TYW ushorts

    stage1_kernel <<<PREP_BLKS + NATOMS, 256, 0, stream>>>(itype, nlist, dR,
                                                           W0, W1, W2,
                                                           order, wsu, featp);
    mlp_kernel    <<<MLP_BLOCKS, 512, 0, stream>>>(featp, itype, order, wsu,
                                                   B0, B1, B2, W3, B3, Ei, dEp);
    force_kernel  <<<Bn * GPB, FTHREADS, 0, stream>>>(itype, nlist, dR, dEp, partial);
    freduce_kernel<<<49, 256, 0, stream>>>(partial, Ei, Force, Etot);
}